// Round 4
// baseline (276.497 us; speedup 1.0000x reference)
//
#include <hip/hip_runtime.h>

#define BATCH 64
#define D1 1024
#define D2 256
#define BPB 32                    // blocks per batch
#define THREADS 256
#define ITERS 8                   // 32 blocks * 8 iters * 768 f4 = 196608 f4 = one batch
#define SEG_F4 (THREADS * 3)      // 768 float4 = 12 KB per block-iteration

// Each block-iteration stages a contiguous 12 KB segment:
//   global->LDS: 3 lane-major float4 loads per thread (perfectly coalesced, 1 KB/instr)
//   LDS->reg:    each thread reads its own 12 contiguous floats (3x ds_read_b128,
//                48 B stride: 8 lanes cover all 32 banks exactly once -> conflict-free)
// Register-staged pipeline: next segment's global loads issued before computing
// on the current one, hiding HBM latency under transcendental work + barriers.

__global__ __launch_bounds__(THREADS) void score_sum_kernel(
        const float* __restrict__ z,
        const float* __restrict__ R,
        float* __restrict__ partial) {
    const int b = blockIdx.y;
    const int tid = threadIdx.x;

    const float Rb = R[b];
    const float Bc = -0.5f / (Rb * Rb);          // -0.5 * A

    const float4* __restrict__ zb4 =
        (const float4*)z + (size_t)b * ((size_t)(D1 * D2 * 3) / 4);

    __shared__ float4 buf[SEG_F4];
    const float* lds_f = (const float*)buf;

    float acc = 0.0f;

    // prologue: stage segment 0
    int seg = blockIdx.x;
    {
        const size_t base = (size_t)seg * SEG_F4 + tid;
        float4 p0 = zb4[base];
        float4 p1 = zb4[base + THREADS];
        float4 p2 = zb4[base + 2 * THREADS];
        buf[tid] = p0;
        buf[tid + THREADS] = p1;
        buf[tid + 2 * THREADS] = p2;
    }
    __syncthreads();

    for (int it = 0; it < ITERS; ++it) {
        const bool more = (it + 1 < ITERS);
        float4 r0, r1, r2;
        if (more) {
            const size_t base = (size_t)(seg + BPB) * SEG_F4 + tid;
            r0 = zb4[base];
            r1 = zb4[base + THREADS];
            r2 = zb4[base + 2 * THREADS];
        }

        // consume current segment: 12 contiguous floats per thread (4 triples)
        const float4* my = (const float4*)(lds_f + 12 * tid);
        const float4 a = my[0];
        const float4 c = my[1];
        const float4 d = my[2];
        const float n0 = sqrtf(fmaf(a.x, a.x, fmaf(a.y, a.y, a.z * a.z)));
        const float n1 = sqrtf(fmaf(a.w, a.w, fmaf(c.x, c.x, c.y * c.y)));
        const float n2 = sqrtf(fmaf(c.z, c.z, fmaf(c.w, c.w, d.x * d.x)));
        const float n3 = sqrtf(fmaf(d.y, d.y, fmaf(d.z, d.z, d.w * d.w)));
        acc += __expf(Bc * n0) + __expf(Bc * n1) + __expf(Bc * n2) + __expf(Bc * n3);

        __syncthreads();                    // all LDS reads of this segment done
        if (more) {
            buf[tid] = r0;
            buf[tid + THREADS] = r1;
            buf[tid + 2 * THREADS] = r2;
        }
        __syncthreads();                    // next segment visible
        seg += BPB;
    }

    // wave (64) shuffle reduce, then cross-wave via LDS
    const int lane = threadIdx.x & 63;
    const int wave = threadIdx.x >> 6;
    for (int off = 32; off; off >>= 1) acc += __shfl_down(acc, off, 64);

    __shared__ float red[THREADS / 64];
    if (lane == 0) red[wave] = acc;
    __syncthreads();
    if (threadIdx.x == 0) {
        partial[b * BPB + blockIdx.x] = red[0] + red[1] + red[2] + red[3];
    }
}

// i0e(x) for large x via the asymptotic series:
// i0e(x) = [1 + 1/(8x) + 9/(2!(8x)^2) + 225/(3!(8x)^3) + ...] / sqrt(2*pi*x)
// truncation < 1e-10 relative for x >= 100 (A in [100, 2500], 2A <= 5000)
__device__ inline double i0e_large(double x) {
    const double ix = 1.0 / x;
    const double s = 1.0 + ix * (0.125
                   + ix * (0.0703125
                   + ix * (0.0732421875
                   + ix * (0.112152099609375
                   + ix * 0.22711181640625))));
    return s / sqrt(6.283185307179586476925286766559 * x);
}

__global__ __launch_bounds__(64) void finalize_kernel(
        const float* __restrict__ partial,
        const float* __restrict__ R,
        const int* __restrict__ num_obs_p,
        float* __restrict__ out) {
    const int b = blockIdx.x;
    const int t = threadIdx.x;

    float v = (t < BPB) ? partial[b * BPB + t] : 0.0f;
    for (int off = 32; off; off >>= 1) v += __shfl_down(v, off, 64);

    if (t == 0) {
        const double nobs = (double)num_obs_p[0];
        const double Rb = (double)R[b];
        const double A = 1.0 / (Rb * Rb);

        // 3D sphere moments
        const double e2 = exp(-2.0 * A);
        const double e4 = exp(-4.0 * A);
        const double mean3 = (1.0 - e2) / (2.0 * A);
        const double ms2_3 = (1.0 - e4) / (4.0 * A);
        const double var3 = ms2_3 - mean3 * mean3;

        // 2D circle moments via i0e
        const double i0eA  = i0e_large(A);
        const double i0e2A = i0e_large(2.0 * A);
        const double var2 = i0e2A - i0eA * i0eA;

        const double WT3 = 0.95, WT2 = 0.05;
        const double mu     = nobs * (WT3 * mean3 + WT2 * i0eA);
        const double sigma2 = nobs * (WT3 * var3  + WT2 * var2);
        const double raw    = (double)v;
        const double objective = raw - mu;   // ALPHA=1, BETA=0

        out[b]             = (float)raw;
        out[BATCH + b]     = (float)mu;
        out[2 * BATCH + b] = (float)sigma2;
        out[3 * BATCH + b] = (float)objective;
    }
}

extern "C" void kernel_launch(void* const* d_in, const int* in_sizes, int n_in,
                              void* d_out, int out_size, void* d_ws, size_t ws_size,
                              hipStream_t stream) {
    const float* z    = (const float*)d_in[0];
    const float* R    = (const float*)d_in[1];
    const int*   nobs = (const int*)d_in[2];
    float* out = (float*)d_out;
    float* partial = (float*)d_ws;   // BATCH * BPB floats = 8 KB

    dim3 grid(BPB, BATCH);
    score_sum_kernel<<<grid, THREADS, 0, stream>>>(z, R, partial);
    finalize_kernel<<<BATCH, 64, 0, stream>>>(partial, R, nobs, out);
}